// Round 11
// baseline (107.807 us; speedup 1.0000x reference)
//
#include <hip/hip_runtime.h>

// Problem constants (reference: B=32, L=64, C=4)
#define BB 32
#define LL 64
#define LC 256
#define NPAIR 2016
#define PPB 8                 // pairs per block
#define NBLK (NPAIR / PPB)    // 252 blocks ~ 1/CU
#define WSTR 256              // ws partial stride per b (floats); NBLK<=256

// v7 (resubmit x2; rounds 9-10 never acquired a GPU). Best-skeleton (v2's
// two plain-store kernels, no memset, no atomics) x best-amortization
// (PPB=8). Evidence to date: dur ~= 83us (2x41us unconditional 256MiB
// ws-poison fills @ ~80% HBM peak) + gaps + kernels; v2=105.6, v6=107.0
// (noise-equivalent); coop sync 210 and flag-spin 216 are dead ends.
// This shrinks both kernels: codes amortized over 8 pairs; reduce reads
// 252 partials/b (8x fewer than v2).
//   1) pair_kernel: 252 blocks x 8 pairs, coalesced float4 theta3 rows,
//      partial -> plain store ws[b*256 + j]  (32KB total)
//   2) reduce_kernel: 32 blocks (1/b), 256 threads: sum 252 partials +
//      theta1 (argmax from x) + theta0 -> out[b]
__global__ __launch_bounds__(256) void pair_kernel(
    const float* __restrict__ x, const float* __restrict__ t2,
    const float* __restrict__ t3, float* __restrict__ ws)
{
    const int tid = threadIdx.x;
    const int j = blockIdx.x;
    const int b = tid >> 3, k = tid & 7;
    const float4* __restrict__ x4 = (const float4*)x + b * 64;

    // codes for my 8 w's (w = 8m+k): once per block, reused across 8 pairs
    int c[8];
#pragma unroll
    for (int m = 0; m < 8; ++m) {
        float4 f = x4[8 * m + k];
        int ci = 0; float best = f.x;
        if (f.y > best) { best = f.y; ci = 1; }
        if (f.z > best) { best = f.z; ci = 2; }
        if (f.w > best) { best = f.w; ci = 3; }
        c[m] = ci;
    }

    // decode first pair index t = v*(v-1)/2 + u for this block
    const int tp0 = j * PPB;
    int v = (int)((1.0f + sqrtf(8.0f * (float)tp0 + 1.0f)) * 0.5f);
    while (v * (v - 1) / 2 > tp0) --v;
    while ((v + 1) * v / 2 <= tp0) ++v;
    int u = tp0 - v * (v - 1) / 2;

    float acc = 0.0f;
#pragma unroll
    for (int i = 0; i < PPB; ++i) {
        float4 fu = x4[u], fv = x4[v];   // block-uniform, L1 broadcast
        int cu = 0; { float bst = fu.x;
            if (fu.y > bst) { bst = fu.y; cu = 1; }
            if (fu.z > bst) { bst = fu.z; cu = 2; }
            if (fu.w > bst) { bst = fu.w; cu = 3; } }
        int cv = 0; { float bst = fv.x;
            if (fv.y > bst) { bst = fv.y; cv = 1; }
            if (fv.z > bst) { bst = fv.z; cv = 2; }
            if (fv.w > bst) { bst = fv.w; cv = 3; } }
        const int pu = 4 * u + cu, pv = 4 * v + cv;

        const float4* __restrict__ row4 =
            (const float4*)(t3 + ((size_t)pu << 16) + ((size_t)pv << 8));
        if (k == 0) acc += t2[pu * LC + pv];   // theta2 term

#pragma unroll
        for (int m = 0; m < 8; ++m) {
            const int w = 8 * m + k;
            float4 f = row4[w];                 // coalesced 16B, in-bounds
            const int ci = c[m];
            float lo = (ci & 1) ? f.y : f.x;    // cndmask chain, no scratch
            float hi = (ci & 1) ? f.w : f.z;
            float val = (ci & 2) ? hi : lo;
            acc += (w > v) ? val : 0.0f;        // strict-triangle mask
        }

        ++u; if (u == v) { u = 0; ++v; }        // next pair (triangular order)
    }

    // width-8 shuffle reduce over k, plain store per-(block,b) partial
    acc += __shfl_down(acc, 4, 8);
    acc += __shfl_down(acc, 2, 8);
    acc += __shfl_down(acc, 1, 8);
    if (k == 0) ws[b * WSTR + j] = acc;
}

// 32 blocks (one per b), 256 threads: sum 252 partials + theta1 + theta0.
__global__ __launch_bounds__(256) void reduce_kernel(
    const float* __restrict__ x, const float* __restrict__ t0,
    const float* __restrict__ t1, const float* __restrict__ ws,
    float* __restrict__ out)
{
    const int b = blockIdx.x;
    const int tid = threadIdx.x;
    float s = (tid < NBLK) ? ws[b * WSTR + tid] : 0.0f;   // coalesced
    if (tid < LL) {
        float4 f = ((const float4*)x)[b * 64 + tid];
        int c = 0; float best = f.x;
        if (f.y > best) { best = f.y; c = 1; }
        if (f.z > best) { best = f.z; c = 2; }
        if (f.w > best) { best = f.w; c = 3; }
        s += t1[4 * tid + c];
    }
    for (int off = 32; off > 0; off >>= 1) s += __shfl_down(s, off, 64);
    __shared__ float wsum[4];
    if ((tid & 63) == 0) wsum[tid >> 6] = s;
    __syncthreads();
    if (tid == 0) out[b] = wsum[0] + wsum[1] + wsum[2] + wsum[3] + t0[0];
}

extern "C" void kernel_launch(void* const* d_in, const int* in_sizes, int n_in,
                              void* d_out, int out_size, void* d_ws, size_t ws_size,
                              hipStream_t stream) {
    const float* x  = (const float*)d_in[0];  // (B, L*C)
    const float* t0 = (const float*)d_in[1];  // (1,)
    const float* t1 = (const float*)d_in[2];  // (L, C)
    const float* t2 = (const float*)d_in[3];  // (L, C, L, C)
    const float* t3 = (const float*)d_in[4];  // (L, C, L, C, L, C)
    float* out = (float*)d_out;               // (B, 1)
    float* ws  = (float*)d_ws;                // uses 32*256 floats = 32 KB

    pair_kernel<<<NBLK, 256, 0, stream>>>(x, t2, t3, ws);
    reduce_kernel<<<BB, 256, 0, stream>>>(x, t0, t1, ws, out);
}